// Round 6
// baseline (161.719 us; speedup 1.0000x reference)
//
#include <hip/hip_runtime.h>
#include <hip/hip_bf16.h>

// Problem constants
#define NQ 8192            // B*S flattened tokens
#define DIM 64             // embed dim
#define SPLITS 16          // key-dimension split (partials merged by kernel 3)
#define QBLK 128           // queries per block (4 waves x 32)
#define BN 64              // keys per tile
#define KEYS_PER_SPLIT (NQ / SPLITS)       // 512
#define NTILES (KEYS_PER_SPLIT / BN)       // 8
#define GRID_FLASH ((NQ / QBLK) * SPLITS)  // 1024
#define MERGEB 256         // merge grid
#define MROWS (NQ / MERGEB)                // 32 rows per merge block
#define SC2 0.51012301920911057f           // (1/sqrt(8)) * log2(e)

#define KSTR 72            // LDS row stride in shorts (qkv/merge tiles)

typedef short s8v __attribute__((ext_vector_type(8)));   // 8 x bf16 bits
typedef short s4v __attribute__((ext_vector_type(4)));   // 4 x bf16 bits
typedef float f4v __attribute__((ext_vector_type(4)));
typedef int   i4v __attribute__((ext_vector_type(4)));

__device__ __forceinline__ float b2f(short s) {
  unsigned int u = ((unsigned int)(unsigned short)s) << 16;
  return __uint_as_float(u);
}
__device__ __forceinline__ short f2b(float f) {
  __hip_bfloat16 h = __float2bfloat16(f);
  return *reinterpret_cast<short*>(&h);
}
__device__ __forceinline__ int pack_bf16x2(float a, float b) {
  union { __hip_bfloat162 h; int i; } u;
  u.h = __float22bfloat162_rn(make_float2(a, b));
  return u.i;
}

// ---------------- QKV projection + quantum map (fp32 in, bf16 out) ----------
// q_q[n,e] = cos(theta[e]) * cos( sum_d x[n,d]*W[e,d] + b[e] )
// V is written TRANSPOSED + MFMA-PERMUTED: vqT[e][ (n&~31) + p(n&31) ] where
// p(i) = ((i>>2)&3)*8 + (i&3) + ((i>>4)<<2)  -- so flash's PV B-frag is one
// aligned b128 load: vqT[d*NQ + g*32 + quad*8 .. +7] holds keys
// g*32 + quad*4 + (j&3) + 16*(j>>2) in exactly the K=32 concat order.
#define QROWS 16
__global__ __launch_bounds__(256) void qkv_kernel(
    const float* __restrict__ x,
    const float* __restrict__ wq, const float* __restrict__ bq,
    const float* __restrict__ wk, const float* __restrict__ bk,
    const float* __restrict__ wv, const float* __restrict__ bv,
    const float* __restrict__ theta,
    short* __restrict__ qq, short* __restrict__ kq, short* __restrict__ vqT) {
  __shared__ __align__(16) short wsh[3][DIM][KSTR];  // bf16 weights
  __shared__ __align__(16) short xsb[QROWS][DIM];    // bf16 x rows
  int tid = threadIdx.x;
  for (int i = tid; i < 3 * DIM * 16; i += 256) {
    int m = i >> 10;
    int rem = i & 1023;
    int r = rem >> 4, c4 = (rem & 15) << 2;
    const float* src = (m == 0) ? wq : (m == 1) ? wk : wv;
    float4 w = *(const float4*)&src[r * DIM + c4];
    s4v p = {f2b(w.x), f2b(w.y), f2b(w.z), f2b(w.w)};
    *(s4v*)&wsh[m][r][c4] = p;
  }
  int rowbase = blockIdx.x * QROWS;
  for (int i = tid; i < QROWS * 16; i += 256) {
    int r = i >> 4, c4 = (i & 15) << 2;
    float4 v = *(const float4*)&x[(rowbase + r) * DIM + c4];
    s4v p = {f2b(v.x), f2b(v.y), f2b(v.z), f2b(v.w)};
    *(s4v*)&xsb[r][c4] = p;
  }
  __syncthreads();
  int e = tid & 63, rg = tid >> 6;
  float ct = __cosf(theta[e]);
  float bqv = bq[e], bkv = bk[e], bvv = bv[e];
  for (int r = rg; r < QROWS; r += 4) {
    float aq = bqv, ak = bkv, av = bvv;
#pragma unroll
    for (int c8 = 0; c8 < 8; ++c8) {
      s8v xv = *(const s8v*)&xsb[r][c8 * 8];
      s8v w0 = *(const s8v*)&wsh[0][e][c8 * 8];
      s8v w1 = *(const s8v*)&wsh[1][e][c8 * 8];
      s8v w2 = *(const s8v*)&wsh[2][e][c8 * 8];
#pragma unroll
      for (int j = 0; j < 8; ++j) {
        float xf = b2f(xv[j]);
        aq += xf * b2f(w0[j]);
        ak += xf * b2f(w1[j]);
        av += xf * b2f(w2[j]);
      }
    }
    int n = rowbase + r;
    qq[n * DIM + e] = f2b(ct * __cosf(aq));
    kq[n * DIM + e] = f2b(ct * __cosf(ak));
    int i32 = n & 31;
    int p = ((i32 >> 2) & 3) * 8 + (i32 & 3) + ((i32 >> 4) << 2);
    vqT[(size_t)e * NQ + (n & ~31) + p] = f2b(ct * __cosf(av));
  }
}

// ---------------- Flash attention: NO LDS, NO BARRIERS ----------------------
// |s| <= 64/sqrt(8) = 22.6 -> exp(s) <= 6.6e9, row sums <= 5.5e13: fp32-safe,
// so no running max; split partials merge by pure summation.
// QK computed as S^T (A=K, B=Q): exp'd C-regs are directly a PV A-operand.
// PV uses K=32 MFMA: pai = concat of two 16-key C-tiles gives key order
// kp*32 + quad*4+(j&3)+16*(j>>2); vqT stores V pre-permuted in THAT order, so
// the B-frag is a single aligned b128 global load. All operands stream from
// L2-resident global (qq/kq/vqT = 3 MB) -- waves run fully independently.
__global__ __launch_bounds__(256, 4) void flash_kernel(
    const short* __restrict__ qq, const short* __restrict__ kq,
    const short* __restrict__ vqT,
    short* __restrict__ pO, short* __restrict__ pL) {
  int tid = threadIdx.x;
  int wave = tid >> 6, lane = tid & 63;
  int l15 = lane & 15, quad = lane >> 4;
  int qblock = blockIdx.x >> 4, split = blockIdx.x & 15;
  int qbase = qblock * QBLK + wave * 32;

  // Q B-frags: B[n=query=l15][k=dim=quad*8+j], two k-halves
  s8v qf[2][2];
#pragma unroll
  for (int qt = 0; qt < 2; ++qt) {
    const short* qr = qq + (qbase + qt * 16 + l15) * DIM + quad * 8;
    qf[qt][0] = *(const s8v*)qr;
    qf[qt][1] = *(const s8v*)(qr + 32);
  }

  f4v o[2][4];
  float ls[2] = {0.f, 0.f};
#pragma unroll
  for (int qt = 0; qt < 2; ++qt)
#pragma unroll
    for (int c = 0; c < 4; ++c) o[qt][c] = (f4v){0.f, 0.f, 0.f, 0.f};

  int kstart = split * KEYS_PER_SPLIT;
  for (int t = 0; t < NTILES; ++t) {
    int kbase = kstart + t * BN;
    // K A-frags from global: A[m=key=l15][k=dim=quad*8+j]
    s8v kf[4][2];
#pragma unroll
    for (int kt = 0; kt < 4; ++kt) {
      const short* kr = &kq[(kbase + kt * 16 + l15) * DIM + quad * 8];
      kf[kt][0] = *(const s8v*)kr;
      kf[kt][1] = *(const s8v*)(kr + 32);
    }
    // V B-frags from pre-permuted global: one b128 per (kp,c)
    s8v vf[2][4];
#pragma unroll
    for (int kp = 0; kp < 2; ++kp)
#pragma unroll
      for (int c = 0; c < 4; ++c)
        vf[kp][c] = *(const s8v*)&vqT[(size_t)(c * 16 + l15) * NQ + kbase +
                                      kp * 32 + quad * 8];

#pragma unroll
    for (int kp = 0; kp < 2; ++kp) {   // pair of 16-key sub-tiles
      i4v pai[2];                      // exp'd P, A-operand bits, per qt
#pragma unroll
      for (int h = 0; h < 2; ++h) {
        int kt = kp * 2 + h;
#pragma unroll
        for (int qt = 0; qt < 2; ++qt) {
          f4v acc = (f4v){0.f, 0.f, 0.f, 0.f};
          acc = __builtin_amdgcn_mfma_f32_16x16x32_bf16(kf[kt][0], qf[qt][0], acc, 0, 0, 0);
          acc = __builtin_amdgcn_mfma_f32_16x16x32_bf16(kf[kt][1], qf[qt][1], acc, 0, 0, 0);
          // acc[r] = S^T[key=kt*16+quad*4+r][query=qt*16+l15]
          float p0 = exp2f(acc[0] * SC2), p1 = exp2f(acc[1] * SC2);
          float p2 = exp2f(acc[2] * SC2), p3 = exp2f(acc[3] * SC2);
          ls[qt] += (p0 + p1) + (p2 + p3);
          pai[qt][h * 2]     = pack_bf16x2(p0, p1);
          pai[qt][h * 2 + 1] = pack_bf16x2(p2, p3);
        }
      }
#pragma unroll
      for (int c = 0; c < 4; ++c)
#pragma unroll
        for (int qt = 0; qt < 2; ++qt)
          o[qt][c] = __builtin_amdgcn_mfma_f32_16x16x32_bf16(
              __builtin_bit_cast(s8v, pai[qt]), vf[kp][c], o[qt][c], 0, 0, 0);
    }
  }

  // finish per-query row sums across quads (lane bits 4,5)
#pragma unroll
  for (int qt = 0; qt < 2; ++qt) {
    float v = ls[qt];
    v += __shfl_xor(v, 16);
    v += __shfl_xor(v, 32);
    ls[qt] = v;
  }

  // store bf16 partials + row sums
#pragma unroll
  for (int qt = 0; qt < 2; ++qt) {
#pragma unroll
    for (int r = 0; r < 4; ++r) {
      int q = qbase + qt * 16 + quad * 4 + r;
      size_t ob = ((size_t)split * NQ + q) * DIM;
#pragma unroll
      for (int c = 0; c < 4; ++c)
        pO[ob + c * 16 + l15] = f2b(o[qt][c][r]);
    }
    if (quad == 0) pL[split * NQ + qbase + qt * 16 + l15] = f2b(ls[qt]);
  }
}

// ---------------- merge partials + output projection (fp32 out) -------------
__global__ __launch_bounds__(256) void merge_kernel(
    const short* __restrict__ pO, const short* __restrict__ pL,
    const float* __restrict__ wo, const float* __restrict__ bo,
    float* __restrict__ out) {
  __shared__ __align__(16) short wsh[DIM * KSTR];
  __shared__ __align__(16) float att[MROWS * DIM];
  int tid = threadIdx.x;
  int q0 = blockIdx.x * MROWS;
  for (int i = tid; i < DIM * 16; i += 256) {
    int r = i >> 4, c4 = (i & 15) << 2;
    float4 w = *(const float4*)&wo[r * DIM + c4];
    s4v p = {f2b(w.x), f2b(w.y), f2b(w.z), f2b(w.w)};
    *(s4v*)&wsh[r * KSTR + c4] = p;
  }
  int e = tid & 63, rg = tid >> 6;
  for (int rr = rg; rr < MROWS; rr += 4) {
    int q = q0 + rr;
    float s = 0.f, l = 0.f;
#pragma unroll
    for (int sp = 0; sp < SPLITS; ++sp) {
      s += b2f(pO[((size_t)sp * NQ + q) * DIM + e]);
      l += b2f(pL[sp * NQ + q]);
    }
    att[rr * DIM + e] = s / l;
  }
  __syncthreads();
  for (int rr = rg; rr < MROWS; rr += 4) {
    float acc = bo[e];
#pragma unroll
    for (int c8 = 0; c8 < 8; ++c8) {
      s8v w = *(const s8v*)&wsh[e * KSTR + c8 * 8];
      const float* ar = &att[rr * DIM + c8 * 8];
      acc += ar[0] * b2f(w[0]) + ar[1] * b2f(w[1]) + ar[2] * b2f(w[2]) + ar[3] * b2f(w[3])
           + ar[4] * b2f(w[4]) + ar[5] * b2f(w[5]) + ar[6] * b2f(w[6]) + ar[7] * b2f(w[7]);
    }
    out[(size_t)(q0 + rr) * DIM + e] = acc;
  }
}

extern "C" void kernel_launch(void* const* d_in, const int* in_sizes, int n_in,
                              void* d_out, int out_size, void* d_ws, size_t ws_size,
                              hipStream_t stream) {
  const float* x  = (const float*)d_in[0];
  const float* wq = (const float*)d_in[1];
  const float* bq = (const float*)d_in[2];
  const float* wk = (const float*)d_in[3];
  const float* bk = (const float*)d_in[4];
  const float* wv = (const float*)d_in[5];
  const float* bv = (const float*)d_in[6];
  const float* th = (const float*)d_in[7];
  const float* wo = (const float*)d_in[8];
  const float* bo = (const float*)d_in[9];

  char* ws = (char*)d_ws;
  short* qq  = (short*)(ws);                            // 1 MB
  short* kq  = (short*)(ws + (1u << 20));               // 1 MB
  short* vqT = (short*)(ws + (2u << 20));               // 1 MB (transposed+perm)
  short* pO  = (short*)(ws + (3u << 20));               // 16 MB bf16 partials
  short* pL  = (short*)(ws + (19u << 20));              // 256 KB bf16 row sums

  hipLaunchKernelGGL(qkv_kernel, dim3(NQ / QROWS), dim3(256), 0, stream,
                     x, wq, bq, wk, bk, wv, bv, th, qq, kq, vqT);
  hipLaunchKernelGGL(flash_kernel, dim3(GRID_FLASH), dim3(256), 0, stream,
                     qq, kq, vqT, pO, pL);
  hipLaunchKernelGGL(merge_kernel, dim3(MERGEB), dim3(256), 0, stream,
                     pO, pL, wo, bo, (float*)d_out);
}

// Round 7
// 133.998 us; speedup vs baseline: 1.2069x; 1.2069x over previous
//
#include <hip/hip_runtime.h>
#include <hip/hip_bf16.h>

// Problem constants
#define NQ 8192            // B*S flattened tokens
#define DIM 64             // embed dim
#define SPLITS 16          // key-dimension split (partials merged by kernel 3)
#define QBLK 128           // queries per block (2 waves x 64)
#define WQ 64              // queries per wave
#define BN 64              // keys per tile
#define KEYS_PER_SPLIT (NQ / SPLITS)       // 512
#define NTILES (KEYS_PER_SPLIT / BN)       // 8
#define GRID_FLASH ((NQ / QBLK) * SPLITS)  // 1024
#define MERGEB 256         // merge grid
#define MROWS (NQ / MERGEB)                // 32 rows per merge block
#define SC2 0.51012301920911057f           // (1/sqrt(8)) * log2(e)
#define KSTR 72            // LDS row stride in shorts (qkv/merge weight tiles)

typedef short s8v __attribute__((ext_vector_type(8)));   // 8 x bf16 bits
typedef short s4v __attribute__((ext_vector_type(4)));   // 4 x bf16 bits
typedef float f4v __attribute__((ext_vector_type(4)));
typedef int   i4v __attribute__((ext_vector_type(4)));
typedef int   i2v __attribute__((ext_vector_type(2)));

__device__ __forceinline__ float b2f(short s) {
  unsigned int u = ((unsigned int)(unsigned short)s) << 16;
  return __uint_as_float(u);
}
__device__ __forceinline__ short f2b(float f) {
  __hip_bfloat16 h = __float2bfloat16(f);
  return *reinterpret_cast<short*>(&h);
}
__device__ __forceinline__ int pack_bf16x2(float a, float b) {
  union { __hip_bfloat162 h; int i; } u;
  u.h = __float22bfloat162_rn(make_float2(a, b));
  return u.i;
}

// ---------------- QKV projection + quantum map (fp32 in, bf16 out) ----------
// q_q[n,e] = cos(theta[e]) * cos( sum_d x[n,d]*W[e,d] + b[e] )
// K and V are written to kvT in FRAGMENT-LINEAR TILED order (8192 shorts per
// 64-key tile: 8 K-chunks then 8 V-chunks of 512 shorts = chunk*512+lane*8+j),
// so flash can stage tiles with linear, conflict-free b128/DMA copies and read
// MFMA fragments at lds[chunk*512 + lane*8] with zero repack.
//   K frag (kt,h): element(key,dim): chunk=kt*2+h (kt=(key&63)>>4, h=dim>>5),
//     lane=((dim&31)>>3)*16 + (key&15), j=dim&7.
//   V frag (kp,c): element(key,dim): chunk=8+kp*4+c (kp=(key&63)>>5, c=dim>>4),
//     lane=((key&15)>>2)*16 + (dim&15), j=(key&3)|((key&16)>>2)  [K=32 perm].
#define QROWS 16
__global__ __launch_bounds__(256) void qkv_kernel(
    const float* __restrict__ x,
    const float* __restrict__ wq, const float* __restrict__ bq,
    const float* __restrict__ wk, const float* __restrict__ bk,
    const float* __restrict__ wv, const float* __restrict__ bv,
    const float* __restrict__ theta,
    short* __restrict__ qq, short* __restrict__ kvT) {
  __shared__ __align__(16) short wsh[3][DIM][KSTR];  // bf16 weights
  __shared__ __align__(16) short xsb[QROWS][DIM];    // bf16 x rows
  int tid = threadIdx.x;
  for (int i = tid; i < 3 * DIM * 16; i += 256) {
    int m = i >> 10;
    int rem = i & 1023;
    int r = rem >> 4, c4 = (rem & 15) << 2;
    const float* src = (m == 0) ? wq : (m == 1) ? wk : wv;
    float4 w = *(const float4*)&src[r * DIM + c4];
    s4v p = {f2b(w.x), f2b(w.y), f2b(w.z), f2b(w.w)};
    *(s4v*)&wsh[m][r][c4] = p;
  }
  int rowbase = blockIdx.x * QROWS;
  for (int i = tid; i < QROWS * 16; i += 256) {
    int r = i >> 4, c4 = (i & 15) << 2;
    float4 v = *(const float4*)&x[(rowbase + r) * DIM + c4];
    s4v p = {f2b(v.x), f2b(v.y), f2b(v.z), f2b(v.w)};
    *(s4v*)&xsb[r][c4] = p;
  }
  __syncthreads();
  int e = tid & 63, rg = tid >> 6;
  float ct = __cosf(theta[e]);
  float bqv = bq[e], bkv = bk[e], bvv = bv[e];
  for (int r = rg; r < QROWS; r += 4) {
    float aq = bqv, ak = bkv, av = bvv;
#pragma unroll
    for (int c8 = 0; c8 < 8; ++c8) {
      s8v xv = *(const s8v*)&xsb[r][c8 * 8];
      s8v w0 = *(const s8v*)&wsh[0][e][c8 * 8];
      s8v w1 = *(const s8v*)&wsh[1][e][c8 * 8];
      s8v w2 = *(const s8v*)&wsh[2][e][c8 * 8];
#pragma unroll
      for (int j = 0; j < 8; ++j) {
        float xf = b2f(xv[j]);
        aq += xf * b2f(w0[j]);
        ak += xf * b2f(w1[j]);
        av += xf * b2f(w2[j]);
      }
    }
    int n = rowbase + r;
    qq[n * DIM + e] = f2b(ct * __cosf(aq));
    size_t tb = (size_t)(n >> 6) * 8192;
    kvT[tb + ((n & 63) >> 4) * 1024 + (e >> 5) * 512 +
        ((e & 31) >> 3) * 128 + (n & 15) * 8 + (e & 7)] = f2b(ct * __cosf(ak));
    kvT[tb + 4096 + ((n & 32) >> 5) * 2048 + (e >> 4) * 512 +
        ((n & 15) >> 2) * 128 + (e & 15) * 8 +
        ((n & 3) | ((n & 16) >> 2))] = f2b(ct * __cosf(av));
  }
}

// ---------------- Flash attention (no-max streaming softmax) ----------------
// |s| <= 64/sqrt(8) = 22.6 -> exp(s) <= 6.6e9, row sums <= 5.5e13: fp32-safe,
// so no running max; split partials merge by pure summation.
// QK computed as S^T (A=K, B=Q): exp'd C-regs are directly a PV A-operand.
// PV uses K=32 MFMA with the key-perm baked into kvT's V chunks.
// Tiles are staged to LDS with global_load_lds (width 16) in fragment-linear
// order: every LDS access is lane*16 linear => conflict-free. Double-buffered,
// ONE barrier per tile. 64 queries/wave halves LDS reads per query.
#if __has_builtin(__builtin_amdgcn_global_load_lds)
#define DMA_CHUNK(srcp, dstp) \
  __builtin_amdgcn_global_load_lds( \
      (const __attribute__((address_space(1))) void*)(srcp), \
      (__attribute__((address_space(3))) void*)(dstp), 16, 0, 0)
#else
#define DMA_CHUNK(srcp, dstp) \
  { *(s8v*)((short*)(dstp) + (threadIdx.x & 63) * 8) = \
        *(const s8v*)((const short*)(srcp)); }
#endif

__global__ __launch_bounds__(128, 2) void flash_kernel(
    const short* __restrict__ qq, const short* __restrict__ kvT,
    short* __restrict__ pO, short* __restrict__ pL) {
  __shared__ __align__(16) short lds[2][8192];  // dbuf: 8 K + 8 V chunks

  int tid = threadIdx.x;
  int wave = tid >> 6, lane = tid & 63;
  int l15 = lane & 15, quad = lane >> 4;
  int qblock = blockIdx.x >> 4, split = blockIdx.x & 15;
  int qbase = qblock * QBLK + wave * WQ;

  // Q B-frags: B[n=query=l15][k=dim=quad*8+j], two k-halves, 4 q-subtiles
  s8v qf[4][2];
#pragma unroll
  for (int qt = 0; qt < 4; ++qt) {
    const short* qr = qq + (qbase + qt * 16 + l15) * DIM + quad * 8;
    qf[qt][0] = *(const s8v*)qr;
    qf[qt][1] = *(const s8v*)(qr + 32);
  }

  f4v o[4][4];
  float ls[4] = {0.f, 0.f, 0.f, 0.f};
#pragma unroll
  for (int qt = 0; qt < 4; ++qt)
#pragma unroll
    for (int c = 0; c < 4; ++c) o[qt][c] = (f4v){0.f, 0.f, 0.f, 0.f};

  int gt0 = split * NTILES;  // first global 64-key tile of this split

  // wave 0 stages the 8 K chunks, wave 1 the 8 V chunks (4 KB each wave)
#define STAGE(T, BUF)                                                        \
  {                                                                          \
    const short* s_ = kvT + (size_t)(gt0 + (T)) * 8192 + wave * 4096 +       \
                      lane * 8;                                              \
    short* d_ = &lds[BUF][wave * 4096];                                      \
    _Pragma("unroll") for (int c2 = 0; c2 < 8; ++c2)                         \
        DMA_CHUNK(s_ + c2 * 512, d_ + c2 * 512);                             \
  }

  STAGE(0, 0)

  for (int t = 0; t < NTILES; ++t) {
    __syncthreads();  // buf t&1 staged; buf (t+1)&1 fully consumed
    if (t + 1 < NTILES) STAGE(t + 1, (t + 1) & 1)

    const short* kb = lds[t & 1];
    const short* vb = lds[t & 1] + 4096;

#pragma unroll
    for (int kp = 0; kp < 2; ++kp) {   // pair of 16-key sub-tiles
      i4v pai[4];                      // exp'd P, A-operand bits, per qt
#pragma unroll
      for (int h = 0; h < 2; ++h) {
        int kt = kp * 2 + h;
        s8v kf0 = *(const s8v*)&kb[(kt * 2) * 512 + lane * 8];
        s8v kf1 = *(const s8v*)&kb[(kt * 2 + 1) * 512 + lane * 8];
#pragma unroll
        for (int qt = 0; qt < 4; ++qt) {
          f4v acc = (f4v){0.f, 0.f, 0.f, 0.f};
          acc = __builtin_amdgcn_mfma_f32_16x16x32_bf16(kf0, qf[qt][0], acc, 0, 0, 0);
          acc = __builtin_amdgcn_mfma_f32_16x16x32_bf16(kf1, qf[qt][1], acc, 0, 0, 0);
          // acc[r] = S^T[key=kt*16+quad*4+r][query=qt*16+l15]
          float p0 = exp2f(acc[0] * SC2), p1 = exp2f(acc[1] * SC2);
          float p2 = exp2f(acc[2] * SC2), p3 = exp2f(acc[3] * SC2);
          ls[qt] += (p0 + p1) + (p2 + p3);
          pai[qt][h * 2]     = pack_bf16x2(p0, p1);
          pai[qt][h * 2 + 1] = pack_bf16x2(p2, p3);
        }
      }
#pragma unroll
      for (int c = 0; c < 4; ++c) {
        s8v vf = *(const s8v*)&vb[(kp * 4 + c) * 512 + lane * 8];
#pragma unroll
        for (int qt = 0; qt < 4; ++qt)
          o[qt][c] = __builtin_amdgcn_mfma_f32_16x16x32_bf16(
              __builtin_bit_cast(s8v, pai[qt]), vf, o[qt][c], 0, 0, 0);
      }
    }
  }

  // finish per-query row sums across quads (lane bits 4,5)
#pragma unroll
  for (int qt = 0; qt < 4; ++qt) {
    float v = ls[qt];
    v += __shfl_xor(v, 16);
    v += __shfl_xor(v, 32);
    ls[qt] = v;
  }

  // store bf16 partials in fragment order (packed dwordx2, fully coalesced):
  // pO[(split*64+qblock)*8192 + ((wave*4+qt)*4+c)*256 + lane*4 + r]
  size_t pb = ((size_t)split * 64 + qblock) * 8192;
#pragma unroll
  for (int qt = 0; qt < 4; ++qt) {
#pragma unroll
    for (int c = 0; c < 4; ++c) {
      i2v pk = {pack_bf16x2(o[qt][c][0], o[qt][c][1]),
                pack_bf16x2(o[qt][c][2], o[qt][c][3])};
      *(i2v*)&pO[pb + (size_t)(((wave * 4 + qt) * 4 + c) * 256 + lane * 4)] = pk;
    }
    if (quad == 0) pL[split * NQ + qbase + qt * 16 + l15] = f2b(ls[qt]);
  }
}

// ---------------- merge partials + output projection (fp32 out) -------------
__global__ __launch_bounds__(256) void merge_kernel(
    const short* __restrict__ pO, const short* __restrict__ pL,
    const float* __restrict__ wo, const float* __restrict__ bo,
    float* __restrict__ out) {
  __shared__ __align__(16) short wsh[DIM * KSTR];
  __shared__ __align__(16) float att[MROWS * DIM];
  int tid = threadIdx.x;
  int q0 = blockIdx.x * MROWS;
  for (int i = tid; i < DIM * 16; i += 256) {
    int r = i >> 4, c4 = (i & 15) << 2;
    float4 w = *(const float4*)&wo[r * DIM + c4];
    s4v p = {f2b(w.x), f2b(w.y), f2b(w.z), f2b(w.w)};
    *(s4v*)&wsh[r * KSTR + c4] = p;
  }
  int e = tid & 63, rg = tid >> 6;
  int c = e >> 4, l15e = e & 15;
  for (int rr = rg; rr < MROWS; rr += 4) {
    int q = q0 + rr;
    // decode flash's fragment-order pO layout
    int qb = q >> 7, wv = (q >> 6) & 1, qt = (q >> 4) & 3;
    int qd = (q >> 2) & 3, r = q & 3;
    size_t base = (size_t)qb * 8192 +
                  (size_t)(((wv * 4 + qt) * 4 + c) * 256 + (qd * 16 + l15e) * 4 + r);
    float s = 0.f, l = 0.f;
#pragma unroll
    for (int sp = 0; sp < SPLITS; ++sp) {
      s += b2f(pO[(size_t)sp * 64 * 8192 + base]);
      l += b2f(pL[sp * NQ + q]);
    }
    att[rr * DIM + e] = s / l;
  }
  __syncthreads();
  for (int rr = rg; rr < MROWS; rr += 4) {
    float acc = bo[e];
#pragma unroll
    for (int c8 = 0; c8 < 8; ++c8) {
      s8v w = *(const s8v*)&wsh[e * KSTR + c8 * 8];
      const float* ar = &att[rr * DIM + c8 * 8];
      acc += ar[0] * b2f(w[0]) + ar[1] * b2f(w[1]) + ar[2] * b2f(w[2]) + ar[3] * b2f(w[3])
           + ar[4] * b2f(w[4]) + ar[5] * b2f(w[5]) + ar[6] * b2f(w[6]) + ar[7] * b2f(w[7]);
    }
    out[(size_t)(q0 + rr) * DIM + e] = acc;
  }
}

extern "C" void kernel_launch(void* const* d_in, const int* in_sizes, int n_in,
                              void* d_out, int out_size, void* d_ws, size_t ws_size,
                              hipStream_t stream) {
  const float* x  = (const float*)d_in[0];
  const float* wq = (const float*)d_in[1];
  const float* bq = (const float*)d_in[2];
  const float* wk = (const float*)d_in[3];
  const float* bk = (const float*)d_in[4];
  const float* wv = (const float*)d_in[5];
  const float* bv = (const float*)d_in[6];
  const float* th = (const float*)d_in[7];
  const float* wo = (const float*)d_in[8];
  const float* bo = (const float*)d_in[9];

  char* ws = (char*)d_ws;
  short* qq  = (short*)(ws);                            // 1 MB  (Q, row-major)
  short* kvT = (short*)(ws + (1u << 20));               // 2 MB  (K+V frag-tiled)
  short* pO  = (short*)(ws + (3u << 20));               // 16 MB bf16 partials
  short* pL  = (short*)(ws + (19u << 20));              // 256 KB bf16 row sums

  hipLaunchKernelGGL(qkv_kernel, dim3(NQ / QROWS), dim3(256), 0, stream,
                     x, wq, bq, wk, bk, wv, bv, th, qq, kvT);
  hipLaunchKernelGGL(flash_kernel, dim3(GRID_FLASH), dim3(128), 0, stream,
                     qq, kvT, pO, pL);
  hipLaunchKernelGGL(merge_kernel, dim3(MERGEB), dim3(256), 0, stream,
                     pO, pL, wo, bo, (float*)d_out);
}

// Round 8
// 120.214 us; speedup vs baseline: 1.3453x; 1.1147x over previous
//
#include <hip/hip_runtime.h>
#include <hip/hip_bf16.h>

// Problem constants
#define NQ 8192            // B*S flattened tokens
#define DIM 64             // embed dim
#define SPLITS 16          // key-dimension split (partials merged by kernel 3)
#define QBLK 128           // queries per block (2 waves x 64)
#define WQ 64              // queries per wave
#define BN 64              // keys per tile
#define KEYS_PER_SPLIT (NQ / SPLITS)       // 512
#define NTILES (KEYS_PER_SPLIT / BN)       // 8
#define GRID_FLASH ((NQ / QBLK) * SPLITS)  // 1024
#define MERGEB 256         // merge grid
#define MROWS (NQ / MERGEB)                // 32 rows per merge block
#define SC2 0.51012301920911057f           // (1/sqrt(8)) * log2(e), folded into qq
#define KSTR 72            // LDS row stride in shorts (qkv/merge weight tiles)

typedef short s8v __attribute__((ext_vector_type(8)));   // 8 x bf16 bits
typedef short s4v __attribute__((ext_vector_type(4)));   // 4 x bf16 bits
typedef float f4v __attribute__((ext_vector_type(4)));
typedef int   i4v __attribute__((ext_vector_type(4)));

__device__ __forceinline__ float b2f(short s) {
  unsigned int u = ((unsigned int)(unsigned short)s) << 16;
  return __uint_as_float(u);
}
__device__ __forceinline__ short f2b(float f) {
  __hip_bfloat16 h = __float2bfloat16(f);
  return *reinterpret_cast<short*>(&h);
}
__device__ __forceinline__ int pack_bf16x2(float a, float b) {
  union { __hip_bfloat162 h; int i; } u;
  u.h = __float22bfloat162_rn(make_float2(a, b));
  return u.i;
}
__device__ __forceinline__ float fast_exp2(float x) {
#if __has_builtin(__builtin_amdgcn_exp2f)
  return __builtin_amdgcn_exp2f(x);   // single v_exp_f32, no OCML call
#else
  return exp2f(x);
#endif
}

// ---------------- QKV projection + quantum map (fp32 in, bf16 out) ----------
// q_q[n,e] = SC2 * cos(theta[e]) * cos( sum_d x[n,d]*W[e,d] + b[e] )  [SC2
// folded: flash applies exp2 directly to the MFMA score].
// K and V go to kvT in FRAGMENT-LINEAR TILED order (8192 shorts per 64-key
// tile: 8 K-chunks then 8 V-chunks of 512 = chunk*512 + lane*8 + j), so flash
// stages tiles with linear conflict-free DMA and reads fragments with zero
// repack. V chunks bake in the K=32 PV key permutation.
#define QROWS 16
__global__ __launch_bounds__(256) void qkv_kernel(
    const float* __restrict__ x,
    const float* __restrict__ wq, const float* __restrict__ bq,
    const float* __restrict__ wk, const float* __restrict__ bk,
    const float* __restrict__ wv, const float* __restrict__ bv,
    const float* __restrict__ theta,
    short* __restrict__ qq, short* __restrict__ kvT) {
  __shared__ __align__(16) short wsh[3][DIM][KSTR];  // bf16 weights
  __shared__ __align__(16) short xsb[QROWS][DIM];    // bf16 x rows
  int tid = threadIdx.x;
  for (int i = tid; i < 3 * DIM * 16; i += 256) {
    int m = i >> 10;
    int rem = i & 1023;
    int r = rem >> 4, c4 = (rem & 15) << 2;
    const float* src = (m == 0) ? wq : (m == 1) ? wk : wv;
    float4 w = *(const float4*)&src[r * DIM + c4];
    s4v p = {f2b(w.x), f2b(w.y), f2b(w.z), f2b(w.w)};
    *(s4v*)&wsh[m][r][c4] = p;
  }
  int rowbase = blockIdx.x * QROWS;
  for (int i = tid; i < QROWS * 16; i += 256) {
    int r = i >> 4, c4 = (i & 15) << 2;
    float4 v = *(const float4*)&x[(rowbase + r) * DIM + c4];
    s4v p = {f2b(v.x), f2b(v.y), f2b(v.z), f2b(v.w)};
    *(s4v*)&xsb[r][c4] = p;
  }
  __syncthreads();
  int e = tid & 63, rg = tid >> 6;
  float ct = __cosf(theta[e]);
  float bqv = bq[e], bkv = bk[e], bvv = bv[e];
  for (int r = rg; r < QROWS; r += 4) {
    float aq = bqv, ak = bkv, av = bvv;
#pragma unroll
    for (int c8 = 0; c8 < 8; ++c8) {
      s8v xv = *(const s8v*)&xsb[r][c8 * 8];
      s8v w0 = *(const s8v*)&wsh[0][e][c8 * 8];
      s8v w1 = *(const s8v*)&wsh[1][e][c8 * 8];
      s8v w2 = *(const s8v*)&wsh[2][e][c8 * 8];
#pragma unroll
      for (int j = 0; j < 8; ++j) {
        float xf = b2f(xv[j]);
        aq += xf * b2f(w0[j]);
        ak += xf * b2f(w1[j]);
        av += xf * b2f(w2[j]);
      }
    }
    int n = rowbase + r;
    qq[n * DIM + e] = f2b(SC2 * ct * __cosf(aq));
    size_t tb = (size_t)(n >> 6) * 8192;
    kvT[tb + ((n & 63) >> 4) * 1024 + (e >> 5) * 512 +
        ((e & 31) >> 3) * 128 + (n & 15) * 8 + (e & 7)] = f2b(ct * __cosf(ak));
    kvT[tb + 4096 + ((n & 32) >> 5) * 2048 + (e >> 4) * 512 +
        ((n & 15) >> 2) * 128 + (e & 15) * 8 +
        ((n & 3) | ((n & 16) >> 2))] = f2b(ct * __cosf(av));
  }
}

// ---------------- Flash attention (no-max streaming softmax) ----------------
// |s| <= 64/sqrt(8) = 22.6 -> exp(s) <= 6.6e9, row sums <= 5.5e13: fp32-safe,
// so no running max; split partials merge by pure summation.
// QK computed as S^T (A=K, B=Q): exp'd C-regs are directly a PV A-operand.
// PV uses K=32 MFMA with the key-perm baked into kvT's V chunks.
// Row sums l computed by an extra MFMA against an all-ones B fragment (no
// VALU adds, no shuffles; l layout == o layout, all columns identical).
#if __has_builtin(__builtin_amdgcn_global_load_lds)
#define DMA_CHUNK(srcp, dstp) \
  __builtin_amdgcn_global_load_lds( \
      (const __attribute__((address_space(1))) void*)(srcp), \
      (__attribute__((address_space(3))) void*)(dstp), 16, 0, 0)
#else
#define DMA_CHUNK(srcp, dstp) \
  { *(s8v*)((short*)(dstp) + (threadIdx.x & 63) * 8) = \
        *(const s8v*)((const short*)(srcp)); }
#endif

__global__ __launch_bounds__(128, 2) void flash_kernel(
    const short* __restrict__ qq, const short* __restrict__ kvT,
    short* __restrict__ pO, short* __restrict__ pL) {
  __shared__ __align__(16) short lds[2][8192];  // dbuf: 8 K + 8 V chunks

  int tid = threadIdx.x;
  int wave = tid >> 6, lane = tid & 63;
  int l15 = lane & 15, quad = lane >> 4;
  int qblock = blockIdx.x >> 4, split = blockIdx.x & 15;
  int qbase = qblock * QBLK + wave * WQ;

  // Q B-frags: B[n=query=l15][k=dim=quad*8+j], two k-halves, 4 q-subtiles
  s8v qf[4][2];
#pragma unroll
  for (int qt = 0; qt < 4; ++qt) {
    const short* qr = qq + (qbase + qt * 16 + l15) * DIM + quad * 8;
    qf[qt][0] = *(const s8v*)qr;
    qf[qt][1] = *(const s8v*)(qr + 32);
  }

  const short ONE = (short)0x3F80;  // bf16 1.0
  const s8v ones = {ONE, ONE, ONE, ONE, ONE, ONE, ONE, ONE};

  f4v o[4][4], ol[4];
#pragma unroll
  for (int qt = 0; qt < 4; ++qt) {
    ol[qt] = (f4v){0.f, 0.f, 0.f, 0.f};
#pragma unroll
    for (int c = 0; c < 4; ++c) o[qt][c] = (f4v){0.f, 0.f, 0.f, 0.f};
  }

  int gt0 = split * NTILES;  // first global 64-key tile of this split

  // wave 0 stages the 8 K chunks, wave 1 the 8 V chunks (4 KB each wave)
#define STAGE(T, BUF)                                                        \
  {                                                                          \
    const short* s_ = kvT + (size_t)(gt0 + (T)) * 8192 + wave * 4096 +       \
                      lane * 8;                                              \
    short* d_ = &lds[BUF][wave * 4096];                                      \
    _Pragma("unroll") for (int c2 = 0; c2 < 8; ++c2)                         \
        DMA_CHUNK(s_ + c2 * 512, d_ + c2 * 512);                             \
  }

  STAGE(0, 0)

  for (int t = 0; t < NTILES; ++t) {
    __syncthreads();  // buf t&1 staged; buf (t+1)&1 fully consumed
    if (t + 1 < NTILES) STAGE(t + 1, (t + 1) & 1)

    const short* kb = lds[t & 1];
    const short* vb = lds[t & 1] + 4096;

#pragma unroll
    for (int kp = 0; kp < 2; ++kp) {   // pair of 16-key sub-tiles
      i4v pai[4];                      // exp'd P, A-operand bits, per qt
#pragma unroll
      for (int h = 0; h < 2; ++h) {
        int kt = kp * 2 + h;
        s8v kf0 = *(const s8v*)&kb[(kt * 2) * 512 + lane * 8];
        s8v kf1 = *(const s8v*)&kb[(kt * 2 + 1) * 512 + lane * 8];
#pragma unroll
        for (int qt = 0; qt < 4; ++qt) {
          f4v acc = (f4v){0.f, 0.f, 0.f, 0.f};
          acc = __builtin_amdgcn_mfma_f32_16x16x32_bf16(kf0, qf[qt][0], acc, 0, 0, 0);
          acc = __builtin_amdgcn_mfma_f32_16x16x32_bf16(kf1, qf[qt][1], acc, 0, 0, 0);
          // acc[r] = SC2*S^T[key=kt*16+quad*4+r][query=qt*16+l15]
          pai[qt][h * 2]     = pack_bf16x2(fast_exp2(acc[0]), fast_exp2(acc[1]));
          pai[qt][h * 2 + 1] = pack_bf16x2(fast_exp2(acc[2]), fast_exp2(acc[3]));
        }
      }
      // row sums via MFMA against ones (accumulates ol; all cols identical)
#pragma unroll
      for (int qt = 0; qt < 4; ++qt)
        ol[qt] = __builtin_amdgcn_mfma_f32_16x16x32_bf16(
            __builtin_bit_cast(s8v, pai[qt]), ones, ol[qt], 0, 0, 0);
#pragma unroll
      for (int c = 0; c < 4; ++c) {
        s8v vf = *(const s8v*)&vb[(kp * 4 + c) * 512 + lane * 8];
#pragma unroll
        for (int qt = 0; qt < 4; ++qt)
          o[qt][c] = __builtin_amdgcn_mfma_f32_16x16x32_bf16(
              __builtin_bit_cast(s8v, pai[qt]), vf, o[qt][c], 0, 0, 0);
      }
    }
  }

  // store bf16 partials: pO[q][split][e] (merge-friendly), pL[q][split]
#pragma unroll
  for (int qt = 0; qt < 4; ++qt) {
#pragma unroll
    for (int r = 0; r < 4; ++r) {
      int q = qbase + qt * 16 + quad * 4 + r;
      short* dst = pO + (size_t)q * (SPLITS * DIM) + split * DIM;
#pragma unroll
      for (int c = 0; c < 4; ++c) dst[c * 16 + l15] = f2b(o[qt][c][r]);
      if (l15 == 0) pL[(size_t)q * SPLITS + split] = f2b(ol[qt][r]);
    }
  }
}

// ---------------- merge partials + output projection (fp32 out) -------------
__global__ __launch_bounds__(256) void merge_kernel(
    const short* __restrict__ pO, const short* __restrict__ pL,
    const float* __restrict__ wo, const float* __restrict__ bo,
    float* __restrict__ out) {
  __shared__ __align__(16) short wsh[DIM * KSTR];
  __shared__ __align__(16) float att[MROWS * DIM];
  int tid = threadIdx.x;
  int q0 = blockIdx.x * MROWS;
  for (int i = tid; i < DIM * 16; i += 256) {
    int r = i >> 4, c4 = (i & 15) << 2;
    float4 w = *(const float4*)&wo[r * DIM + c4];
    s4v p = {f2b(w.x), f2b(w.y), f2b(w.z), f2b(w.w)};
    *(s4v*)&wsh[r * KSTR + c4] = p;
  }
  int wave = tid >> 6, j = tid & 63;
  // phase 1: att rows, fully vectorized; lane j covers sp=j>>3 (+8), e8=j&7
#pragma unroll
  for (int i = 0; i < MROWS / 4; ++i) {
    int rr = wave * (MROWS / 4) + i;
    int q = q0 + rr;
    const short* prow = pO + (size_t)q * (SPLITS * DIM);
    s8v v0 = *(const s8v*)&prow[j * 8];
    s8v v1 = *(const s8v*)&prow[512 + j * 8];
    float a[8];
#pragma unroll
    for (int m = 0; m < 8; ++m) a[m] = b2f(v0[m]) + b2f(v1[m]);
#pragma unroll
    for (int st = 8; st < 64; st <<= 1)
#pragma unroll
      for (int m = 0; m < 8; ++m) a[m] += __shfl_xor(a[m], st);
    const short* lrow = pL + (size_t)q * SPLITS;
    s8v lv0 = *(const s8v*)&lrow[0];
    s8v lv1 = *(const s8v*)&lrow[8];
    float l = 0.f;
#pragma unroll
    for (int m = 0; m < 8; ++m) l += b2f(lv0[m]) + b2f(lv1[m]);
#if __has_builtin(__builtin_amdgcn_rcpf)
    float ri = __builtin_amdgcn_rcpf(l);
#else
    float ri = 1.f / l;
#endif
    if (j < 8) {
      float4 f0 = {a[0] * ri, a[1] * ri, a[2] * ri, a[3] * ri};
      float4 f1 = {a[4] * ri, a[5] * ri, a[6] * ri, a[7] * ri};
      *(float4*)&att[rr * DIM + j * 8] = f0;
      *(float4*)&att[rr * DIM + j * 8 + 4] = f1;
    }
  }
  __syncthreads();
  int e = tid & 63, rg = tid >> 6;
  for (int rr = rg; rr < MROWS; rr += 4) {
    float acc = bo[e];
#pragma unroll
    for (int c8 = 0; c8 < 8; ++c8) {
      s8v w = *(const s8v*)&wsh[e * KSTR + c8 * 8];
      const float* ar = &att[rr * DIM + c8 * 8];
      acc += ar[0] * b2f(w[0]) + ar[1] * b2f(w[1]) + ar[2] * b2f(w[2]) + ar[3] * b2f(w[3])
           + ar[4] * b2f(w[4]) + ar[5] * b2f(w[5]) + ar[6] * b2f(w[6]) + ar[7] * b2f(w[7]);
    }
    out[(size_t)(q0 + rr) * DIM + e] = acc;
  }
}

extern "C" void kernel_launch(void* const* d_in, const int* in_sizes, int n_in,
                              void* d_out, int out_size, void* d_ws, size_t ws_size,
                              hipStream_t stream) {
  const float* x  = (const float*)d_in[0];
  const float* wq = (const float*)d_in[1];
  const float* bq = (const float*)d_in[2];
  const float* wk = (const float*)d_in[3];
  const float* bk = (const float*)d_in[4];
  const float* wv = (const float*)d_in[5];
  const float* bv = (const float*)d_in[6];
  const float* th = (const float*)d_in[7];
  const float* wo = (const float*)d_in[8];
  const float* bo = (const float*)d_in[9];

  char* ws = (char*)d_ws;
  short* qq  = (short*)(ws);                            // 1 MB  (Q, row-major, SC2-scaled)
  short* kvT = (short*)(ws + (1u << 20));               // 2 MB  (K+V frag-tiled)
  short* pO  = (short*)(ws + (3u << 20));               // 16 MB bf16 partials [q][sp][e]
  short* pL  = (short*)(ws + (19u << 20));              // 256 KB bf16 sums [q][sp]

  hipLaunchKernelGGL(qkv_kernel, dim3(NQ / QROWS), dim3(256), 0, stream,
                     x, wq, bq, wk, bk, wv, bv, th, qq, kvT);
  hipLaunchKernelGGL(flash_kernel, dim3(GRID_FLASH), dim3(128), 0, stream,
                     qq, kvT, pO, pL);
  hipLaunchKernelGGL(merge_kernel, dim3(MERGEB), dim3(256), 0, stream,
                     pO, pL, wo, bo, (float*)d_out);
}